// Round 7
// baseline (393.376 us; speedup 1.0000x reference)
//
#include <hip/hip_runtime.h>

// GCN 4-layer forward on MI355X.
// Reference: h' = relu( norm_dst * segsum_{dst}( ((h*norm_src) @ W)[src] ) + b )
//
// Round 7:
//  - fill's 600k atomics removed: deg_loc records le[e]=atomicAdd(degi[dst])
//    while counting; scatter writes col[rowptr[d]+le[e]]=src atomic-free.
//  - GEMM: 8x8 thread tile on 128x128 block tile (256t, 128KB LDS, 1 blk/CU),
//    LDS bytes/FMA 2.0 -> 1.0 (r6 was LDS-pipe-bound at ~40us). W staged in
//    split wlA/wlB so the 16-addr read is 2-way (free); ns folded into ht.

namespace {

constexpr int NN = 50000;      // nodes
constexpr int NE = 600000;     // edges
constexpr int INDIM = 128;
constexpr int SCAN_BLK = 256;
constexpr int NBLK = (NN + SCAN_BLK - 1) / SCAN_BLK;  // 196

// counts out-degree (dego) and in-degree (degi); le[e] = arrival slot of edge
// e within its dst segment (makes the later scatter atomic-free).
__global__ void deg_loc_kernel(const int* __restrict__ src, const int* __restrict__ dst,
                               int* __restrict__ dego, int* __restrict__ degi,
                               int* __restrict__ le) {
  int e = blockIdx.x * blockDim.x + threadIdx.x;
  if (e < NE) {
    atomicAdd(&dego[src[e]], 1);
    le[e] = atomicAdd(&degi[dst[e]], 1);
  }
}

__global__ void norm_kernel(const int* __restrict__ dego, const int* __restrict__ degi,
                            float* __restrict__ ns, float* __restrict__ nd) {
  int i = blockIdx.x * blockDim.x + threadIdx.x;
  if (i < NN) {
    int a = dego[i]; if (a < 1) a = 1;
    int b = degi[i]; if (b < 1) b = 1;
    ns[i] = 1.0f / sqrtf((float)a);
    nd[i] = 1.0f / sqrtf((float)b);
  }
}

// --- 3-phase scan of degi[NN] -> rowptr[NN+1] (exclusive) ---

__global__ __launch_bounds__(SCAN_BLK) void scan_phase1(const int* __restrict__ deg,
                                                        int* __restrict__ bsum) {
  __shared__ int ws[SCAN_BLK / 64];
  int i = blockIdx.x * SCAN_BLK + threadIdx.x;
  int v = (i < NN) ? deg[i] : 0;
#pragma unroll
  for (int off = 32; off; off >>= 1) v += __shfl_down(v, off, 64);
  int lane = threadIdx.x & 63, w = threadIdx.x >> 6;
  if (lane == 0) ws[w] = v;
  __syncthreads();
  if (threadIdx.x == 0) {
    int s = 0;
#pragma unroll
    for (int k = 0; k < SCAN_BLK / 64; ++k) s += ws[k];
    bsum[blockIdx.x] = s;
  }
}

__global__ __launch_bounds__(256) void scan_phase2(const int* __restrict__ bsum,
                                                   int* __restrict__ bpre,
                                                   int* __restrict__ rowptr) {
  __shared__ int s[256];
  int t = threadIdx.x;
  int v = (t < NBLK) ? bsum[t] : 0;
  s[t] = v;
  __syncthreads();
  for (int off = 1; off < 256; off <<= 1) {
    int u = (t >= off) ? s[t - off] : 0;
    __syncthreads();
    s[t] += u;
    __syncthreads();
  }
  if (t < NBLK) bpre[t] = s[t] - v;  // exclusive
  if (t == 255) rowptr[NN] = s[255]; // total == NE
}

__global__ __launch_bounds__(SCAN_BLK) void scan_phase3(const int* __restrict__ deg,
                                                        const int* __restrict__ bpre,
                                                        int* __restrict__ rowptr) {
  __shared__ int s[SCAN_BLK];
  int t = threadIdx.x;
  int i = blockIdx.x * SCAN_BLK + t;
  int v = (i < NN) ? deg[i] : 0;
  s[t] = v;
  __syncthreads();
  for (int off = 1; off < SCAN_BLK; off <<= 1) {
    int u = (t >= off) ? s[t - off] : 0;
    __syncthreads();
    s[t] += u;
    __syncthreads();
  }
  if (i < NN) rowptr[i] = bpre[blockIdx.x] + s[t] - v;
}

// atomic-free CSR fill using precomputed local slots
__global__ void scatter_kernel(const int* __restrict__ src, const int* __restrict__ dst,
                               const int* __restrict__ le, const int* __restrict__ rowptr,
                               int* __restrict__ col) {
  int e = blockIdx.x * blockDim.x + threadIdx.x;
  if (e < NE) col[rowptr[dst[e]] + le[e]] = src[e];
}

// x[row][j] = sum_k (ns[row]*h[row][k]) * W[k][j]   DO=128, K=128
// One block per 128-row group. 256 threads, 8x8 outputs each (rq=tid>>4,
// cq=tid&15). LDS 128KB: ht[k][row] (ns folded, transposed staging: writes
// conflict-free), wlA/wlB split so cols cq*8..+3 / +4..+7 are each a 256B-
// contiguous 16-addr read (2-way, free). ht read = 4-addr broadcast, free.
__global__ __launch_bounds__(256, 1) void gemm_ns128(const float* __restrict__ h,
                                                     const float* __restrict__ W,
                                                     const float* __restrict__ ns,
                                                     float* __restrict__ x) {
  __shared__ __align__(16) float ht[128 * 128];   // 64 KB
  __shared__ __align__(16) float wlA[128 * 64];   // 32 KB
  __shared__ __align__(16) float wlB[128 * 64];   // 32 KB
  const int tid = threadIdx.x;
  const int row0 = blockIdx.x * 128;

  // stage W: [128][128] -> wlA/wlB, coalesced float4 reads
#pragma unroll
  for (int it = 0; it < 16; ++it) {
    int flat = it * 256 + tid;      // 0..4095
    int k = flat >> 5;
    int c4 = flat & 31;
    float4 w4 = *reinterpret_cast<const float4*>(&W[k * 128 + c4 * 4]);
    float* d = (c4 & 1) ? &wlB[k * 64 + (c4 >> 1) * 4] : &wlA[k * 64 + (c4 >> 1) * 4];
    *reinterpret_cast<float4*>(d) = w4;
  }
  // stage h^T with ns folded: row = flat&127 (lane-consecutive -> LDS writes
  // conflict-free), kq = flat>>7; global read strided (L2/L3-hot h)
#pragma unroll
  for (int it = 0; it < 16; ++it) {
    int flat = it * 256 + tid;
    int row = flat & 127;
    int kq = flat >> 7;
    int grow = row0 + row;
    float4 hv = make_float4(0.f, 0.f, 0.f, 0.f);
    float sc = 0.f;
    if (grow < NN) {
      hv = *reinterpret_cast<const float4*>(&h[(size_t)grow * INDIM + kq * 4]);
      sc = ns[grow];
    }
    ht[(kq * 4 + 0) * 128 + row] = hv.x * sc;
    ht[(kq * 4 + 1) * 128 + row] = hv.y * sc;
    ht[(kq * 4 + 2) * 128 + row] = hv.z * sc;
    ht[(kq * 4 + 3) * 128 + row] = hv.w * sc;
  }
  __syncthreads();

  const int rq = tid >> 4;
  const int cq = tid & 15;
  float acc[8][8] = {{0.f}};
#pragma unroll 4
  for (int k = 0; k < 128; ++k) {
    float4 hA = *reinterpret_cast<const float4*>(&ht[k * 128 + rq * 8]);
    float4 hB = *reinterpret_cast<const float4*>(&ht[k * 128 + rq * 8 + 4]);
    float4 wA = *reinterpret_cast<const float4*>(&wlA[k * 64 + cq * 4]);
    float4 wB = *reinterpret_cast<const float4*>(&wlB[k * 64 + cq * 4]);
    float hv[8] = {hA.x, hA.y, hA.z, hA.w, hB.x, hB.y, hB.z, hB.w};
    float wv[8] = {wA.x, wA.y, wA.z, wA.w, wB.x, wB.y, wB.z, wB.w};
#pragma unroll
    for (int i = 0; i < 8; ++i)
#pragma unroll
      for (int j = 0; j < 8; ++j) acc[i][j] = fmaf(hv[i], wv[j], acc[i][j]);
  }

#pragma unroll
  for (int i = 0; i < 8; ++i) {
    int row = row0 + rq * 8 + i;
    if (row < NN) {
      float4 v0 = make_float4(acc[i][0], acc[i][1], acc[i][2], acc[i][3]);
      float4 v1 = make_float4(acc[i][4], acc[i][5], acc[i][6], acc[i][7]);
      *reinterpret_cast<float4*>(&x[(size_t)row * 128 + cq * 8]) = v0;
      *reinterpret_cast<float4*>(&x[(size_t)row * 128 + cq * 8 + 4]) = v1;
    }
  }
}

// DO=64 variant: 128 threads, 8x8 tile (rq=tid>>3, cq=tid&7), 96KB LDS.
__global__ __launch_bounds__(128, 1) void gemm_ns64(const float* __restrict__ h,
                                                    const float* __restrict__ W,
                                                    const float* __restrict__ ns,
                                                    float* __restrict__ x) {
  __shared__ __align__(16) float ht[128 * 128];   // 64 KB
  __shared__ __align__(16) float wlA[128 * 32];   // 16 KB
  __shared__ __align__(16) float wlB[128 * 32];   // 16 KB
  const int tid = threadIdx.x;
  const int row0 = blockIdx.x * 128;

#pragma unroll
  for (int it = 0; it < 16; ++it) {
    int flat = it * 128 + tid;      // 0..2047
    int k = flat >> 4;
    int c4 = flat & 15;
    float4 w4 = *reinterpret_cast<const float4*>(&W[k * 64 + c4 * 4]);
    float* d = (c4 & 1) ? &wlB[k * 32 + (c4 >> 1) * 4] : &wlA[k * 32 + (c4 >> 1) * 4];
    *reinterpret_cast<float4*>(d) = w4;
  }
#pragma unroll
  for (int it = 0; it < 32; ++it) {
    int flat = it * 128 + tid;      // 0..4095
    int row = flat & 127;
    int kq = flat >> 7;
    int grow = row0 + row;
    float4 hv = make_float4(0.f, 0.f, 0.f, 0.f);
    float sc = 0.f;
    if (grow < NN) {
      hv = *reinterpret_cast<const float4*>(&h[(size_t)grow * INDIM + kq * 4]);
      sc = ns[grow];
    }
    ht[(kq * 4 + 0) * 128 + row] = hv.x * sc;
    ht[(kq * 4 + 1) * 128 + row] = hv.y * sc;
    ht[(kq * 4 + 2) * 128 + row] = hv.z * sc;
    ht[(kq * 4 + 3) * 128 + row] = hv.w * sc;
  }
  __syncthreads();

  const int rq = tid >> 3;
  const int cq = tid & 7;
  float acc[8][8] = {{0.f}};
#pragma unroll 4
  for (int k = 0; k < 128; ++k) {
    float4 hA = *reinterpret_cast<const float4*>(&ht[k * 128 + rq * 8]);
    float4 hB = *reinterpret_cast<const float4*>(&ht[k * 128 + rq * 8 + 4]);
    float4 wA = *reinterpret_cast<const float4*>(&wlA[k * 32 + cq * 4]);
    float4 wB = *reinterpret_cast<const float4*>(&wlB[k * 32 + cq * 4]);
    float hv[8] = {hA.x, hA.y, hA.z, hA.w, hB.x, hB.y, hB.z, hB.w};
    float wv[8] = {wA.x, wA.y, wA.z, wA.w, wB.x, wB.y, wB.z, wB.w};
#pragma unroll
    for (int i = 0; i < 8; ++i)
#pragma unroll
      for (int j = 0; j < 8; ++j) acc[i][j] = fmaf(hv[i], wv[j], acc[i][j]);
  }

#pragma unroll
  for (int i = 0; i < 8; ++i) {
    int row = row0 + rq * 8 + i;
    if (row < NN) {
      float4 v0 = make_float4(acc[i][0], acc[i][1], acc[i][2], acc[i][3]);
      float4 v1 = make_float4(acc[i][4], acc[i][5], acc[i][6], acc[i][7]);
      *reinterpret_cast<float4*>(&x[(size_t)row * 64 + cq * 8]) = v0;
      *reinterpret_cast<float4*>(&x[(size_t)row * 64 + cq * 8 + 4]) = v1;
    }
  }
}

// One wave per node. Lane layout: sub = lane/LPR edge slot, c4 = (lane%LPR)*4
// column. LPR lanes cover a D-dim row with float4; EPW=64/LPR edge slots,
// 4 edges per slot in flight. Slot partials combined by shfl_xor; lanes < LPR
// write the coalesced float4 output with nd/bias/relu fused.
template <int D, bool RELU>
__global__ __launch_bounds__(256) void gather_kernel(const float* __restrict__ x,
                                                     const int* __restrict__ rowptr,
                                                     const int* __restrict__ col,
                                                     const float* __restrict__ nd,
                                                     const float* __restrict__ b,
                                                     float* __restrict__ out) {
  constexpr int LPR = D / 4;     // 32 (D=128) or 16 (D=64)
  constexpr int EPW = 64 / LPR;  // 2 or 4
  const int wid = (blockIdx.x * blockDim.x + threadIdx.x) >> 6;
  const int lane = threadIdx.x & 63;
  if (wid >= NN) return;
  const int sub = lane / LPR;
  const int c4 = (lane % LPR) * 4;
  const int beg = rowptr[wid];
  const int end = rowptr[wid + 1];

  float ax = 0.f, ay = 0.f, az = 0.f, aw = 0.f;
  int e = beg + sub;
  for (; e + 3 * EPW < end; e += 4 * EPW) {
    int c0 = col[e];
    int c1 = col[e + EPW];
    int c2 = col[e + 2 * EPW];
    int c3 = col[e + 3 * EPW];
    float4 v0 = *reinterpret_cast<const float4*>(&x[(size_t)c0 * D + c4]);
    float4 v1 = *reinterpret_cast<const float4*>(&x[(size_t)c1 * D + c4]);
    float4 v2 = *reinterpret_cast<const float4*>(&x[(size_t)c2 * D + c4]);
    float4 v3 = *reinterpret_cast<const float4*>(&x[(size_t)c3 * D + c4]);
    ax += (v0.x + v1.x) + (v2.x + v3.x);
    ay += (v0.y + v1.y) + (v2.y + v3.y);
    az += (v0.z + v1.z) + (v2.z + v3.z);
    aw += (v0.w + v1.w) + (v2.w + v3.w);
  }
  for (; e < end; e += EPW) {
    int c0 = col[e];
    float4 v0 = *reinterpret_cast<const float4*>(&x[(size_t)c0 * D + c4]);
    ax += v0.x; ay += v0.y; az += v0.z; aw += v0.w;
  }

#pragma unroll
  for (int off = LPR; off < 64; off <<= 1) {
    ax += __shfl_xor(ax, off, 64);
    ay += __shfl_xor(ay, off, 64);
    az += __shfl_xor(az, off, 64);
    aw += __shfl_xor(aw, off, 64);
  }

  if (lane < LPR) {
    const float s = nd[wid];
    float4 bb = *reinterpret_cast<const float4*>(&b[c4]);
    float4 r;
    r.x = fmaf(ax, s, bb.x);
    r.y = fmaf(ay, s, bb.y);
    r.z = fmaf(az, s, bb.z);
    r.w = fmaf(aw, s, bb.w);
    if (RELU) {
      r.x = fmaxf(r.x, 0.f);
      r.y = fmaxf(r.y, 0.f);
      r.z = fmaxf(r.z, 0.f);
      r.w = fmaxf(r.w, 0.f);
    }
    *reinterpret_cast<float4*>(&out[(size_t)wid * D + c4]) = r;
  }
}

}  // namespace

extern "C" void kernel_launch(void* const* d_in, const int* in_sizes, int n_in,
                              void* d_out, int out_size, void* d_ws, size_t ws_size,
                              hipStream_t stream) {
  const float* h0  = (const float*)d_in[0];
  const int*   src = (const int*)d_in[1];
  const int*   dst = (const int*)d_in[2];
  const float* W0 = (const float*)d_in[3];
  const float* b0 = (const float*)d_in[4];
  const float* W1 = (const float*)d_in[5];
  const float* b1 = (const float*)d_in[6];
  const float* W2 = (const float*)d_in[7];
  const float* b2 = (const float*)d_in[8];
  const float* W3 = (const float*)d_in[9];
  const float* b3 = (const float*)d_in[10];
  float* out = (float*)d_out;

  // workspace layout (256B aligned)
  char* w = (char*)d_ws;
  size_t off = 0;
  auto take = [&](size_t bytes) {
    char* p = w + off;
    off = (off + bytes + 255) & ~size_t(255);
    return p;
  };
  int*   deg_out = (int*)take(NN * 4);   // adjacent: one memset covers both
  int*   deg_in  = (int*)take(NN * 4);
  float* nsrc    = (float*)take(NN * 4);
  float* ndst    = (float*)take(NN * 4);
  int*   rowptr  = (int*)take((NN + 1) * 4);
  int*   le      = (int*)take(NE * 4);
  int*   col     = (int*)take(NE * 4);
  int*   bsum    = (int*)take(NBLK * 4);
  int*   bpre    = (int*)take(NBLK * 4);
  float* xbuf    = (float*)take((size_t)NN * 128 * 4);
  float* hbuf    = (float*)take((size_t)NN * 128 * 4);
  (void)ws_size; (void)in_sizes; (void)n_in; (void)out_size;

  // one memset spanning deg_out..deg_in (contiguous, 256B-padded)
  hipMemsetAsync(deg_out, 0, (size_t)((char*)nsrc - (char*)deg_out), stream);

  const int EB = (NE + 255) / 256;
  const int NB = (NN + 255) / 256;
  deg_loc_kernel<<<EB, 256, 0, stream>>>(src, dst, deg_out, deg_in, le);
  norm_kernel<<<NB, 256, 0, stream>>>(deg_out, deg_in, nsrc, ndst);
  scan_phase1<<<NBLK, SCAN_BLK, 0, stream>>>(deg_in, bsum);
  scan_phase2<<<1, 256, 0, stream>>>(bsum, bpre, rowptr);
  scan_phase3<<<NBLK, SCAN_BLK, 0, stream>>>(deg_in, bpre, rowptr);
  scatter_kernel<<<EB, 256, 0, stream>>>(src, dst, le, rowptr, col);

  const int GEMM_BLOCKS = (NN + 127) / 128;  // 391, one 128-row group each
  const int GATHER_BLOCKS = (NN * 64 + 255) / 256;

  // layer 0: h0 -> x -> hbuf (relu)
  gemm_ns128<<<GEMM_BLOCKS, 256, 0, stream>>>(h0, W0, nsrc, xbuf);
  gather_kernel<128, true><<<GATHER_BLOCKS, 256, 0, stream>>>(xbuf, rowptr, col, ndst, b0, hbuf);
  // layer 1
  gemm_ns128<<<GEMM_BLOCKS, 256, 0, stream>>>(hbuf, W1, nsrc, xbuf);
  gather_kernel<128, true><<<GATHER_BLOCKS, 256, 0, stream>>>(xbuf, rowptr, col, ndst, b1, hbuf);
  // layer 2
  gemm_ns128<<<GEMM_BLOCKS, 256, 0, stream>>>(hbuf, W2, nsrc, xbuf);
  gather_kernel<128, true><<<GATHER_BLOCKS, 256, 0, stream>>>(xbuf, rowptr, col, ndst, b2, hbuf);
  // layer 3: no relu, D=64, straight to d_out
  gemm_ns64<<<GEMM_BLOCKS, 128, 0, stream>>>(hbuf, W3, nsrc, xbuf);
  gather_kernel<64, false><<<GATHER_BLOCKS, 256, 0, stream>>>(xbuf, rowptr, col, ndst, b3, out);
}

// Round 8
// 368.301 us; speedup vs baseline: 1.0681x; 1.0681x over previous
//
#include <hip/hip_runtime.h>

// GCN 4-layer forward on MI355X.
// Reference: h' = relu( norm_dst * segsum_{dst}( ((h*norm_src) @ W)[src] ) + b )
//
// Round 8:
//  - Degree counting: 8 XCD-sharded histogram replicas (blockIdx&7) to stop
//    cross-XCD L2 line ping-pong (r7: 40MB WRITE_SIZE for 2.8MB of logical
//    writes). le packs (slot<<3)|replica; reduce_norm sums replicas + builds
//    per-replica offsets; finalize folds rowptr in; scatter = 1 random read.
//  - GEMM: 64x128 tile, 256t, 4x4/thread per col-half, hs[64][132] row-major
//    (coalesced staging — fixes r6/r7 strided 4x over-fetch; padded for
//    conflict-free b128 reads), 66.5KB LDS -> 2 blocks/CU.

namespace {

constexpr int NN = 50000;      // nodes
constexpr int NE = 600000;     // edges
constexpr int NNP = 50176;     // padded node stride for histogram replicas
constexpr int SCAN_BLK = 256;
constexpr int NBLK = (NN + SCAN_BLK - 1) / SCAN_BLK;  // 196

// 8-sharded degree count; le[e] = (slot within dst's shard-c segment)<<3 | c
__global__ void deg8_kernel(const int* __restrict__ src, const int* __restrict__ dst,
                            int* __restrict__ dego8, int* __restrict__ degi8,
                            int* __restrict__ le) {
  int e = blockIdx.x * blockDim.x + threadIdx.x;
  if (e < NE) {
    const int c = blockIdx.x & 7;
    atomicAdd(&dego8[c * NNP + src[e]], 1);
    int slot = atomicAdd(&degi8[c * NNP + dst[e]], 1);
    le[e] = (slot << 3) | c;
  }
}

// sum replicas -> degi_tot (for scan), norms, per-replica exclusive offsets
__global__ void reduce_norm_kernel(const int* __restrict__ dego8,
                                   const int* __restrict__ degi8,
                                   int* __restrict__ degi_tot,
                                   float* __restrict__ ns, float* __restrict__ nd,
                                   int* __restrict__ offp) {
  int n = blockIdx.x * blockDim.x + threadIdx.x;
  if (n < NN) {
    int si = 0, so = 0;
#pragma unroll
    for (int c = 0; c < 8; ++c) {
      offp[n * 8 + c] = si;
      si += degi8[c * NNP + n];
      so += dego8[c * NNP + n];
    }
    degi_tot[n] = si;
    int a = so < 1 ? 1 : so;
    int b = si < 1 ? 1 : si;
    ns[n] = 1.0f / sqrtf((float)a);
    nd[n] = 1.0f / sqrtf((float)b);
  }
}

// --- 3-phase scan of degi_tot[NN] -> rowptr[NN+1] (exclusive) ---

__global__ __launch_bounds__(SCAN_BLK) void scan_phase1(const int* __restrict__ deg,
                                                        int* __restrict__ bsum) {
  __shared__ int ws[SCAN_BLK / 64];
  int i = blockIdx.x * SCAN_BLK + threadIdx.x;
  int v = (i < NN) ? deg[i] : 0;
#pragma unroll
  for (int off = 32; off; off >>= 1) v += __shfl_down(v, off, 64);
  int lane = threadIdx.x & 63, w = threadIdx.x >> 6;
  if (lane == 0) ws[w] = v;
  __syncthreads();
  if (threadIdx.x == 0) {
    int s = 0;
#pragma unroll
    for (int k = 0; k < SCAN_BLK / 64; ++k) s += ws[k];
    bsum[blockIdx.x] = s;
  }
}

__global__ __launch_bounds__(256) void scan_phase2(const int* __restrict__ bsum,
                                                   int* __restrict__ bpre,
                                                   int* __restrict__ rowptr) {
  __shared__ int s[256];
  int t = threadIdx.x;
  int v = (t < NBLK) ? bsum[t] : 0;
  s[t] = v;
  __syncthreads();
  for (int off = 1; off < 256; off <<= 1) {
    int u = (t >= off) ? s[t - off] : 0;
    __syncthreads();
    s[t] += u;
    __syncthreads();
  }
  if (t < NBLK) bpre[t] = s[t] - v;  // exclusive
  if (t == 255) rowptr[NN] = s[255]; // total == NE
}

__global__ __launch_bounds__(SCAN_BLK) void scan_phase3(const int* __restrict__ deg,
                                                        const int* __restrict__ bpre,
                                                        int* __restrict__ rowptr) {
  __shared__ int s[SCAN_BLK];
  int t = threadIdx.x;
  int i = blockIdx.x * SCAN_BLK + t;
  int v = (i < NN) ? deg[i] : 0;
  s[t] = v;
  __syncthreads();
  for (int off = 1; off < SCAN_BLK; off <<= 1) {
    int u = (t >= off) ? s[t - off] : 0;
    __syncthreads();
    s[t] += u;
    __syncthreads();
  }
  if (i < NN) rowptr[i] = bpre[blockIdx.x] + s[t] - v;
}

// offp[n][c] += rowptr[n]  (so scatter needs a single random read)
__global__ void finalize_off_kernel(const int* __restrict__ rowptr,
                                    int* __restrict__ offp) {
  int n = blockIdx.x * blockDim.x + threadIdx.x;
  if (n < NN) {
    int base = rowptr[n];
#pragma unroll
    for (int c = 0; c < 8; ++c) offp[n * 8 + c] += base;
  }
}

// atomic-free CSR fill
__global__ void scatter_kernel(const int* __restrict__ src, const int* __restrict__ dst,
                               const int* __restrict__ le, const int* __restrict__ offp,
                               int* __restrict__ col) {
  int e = blockIdx.x * blockDim.x + threadIdx.x;
  if (e < NE) {
    int u = le[e];
    col[offp[dst[e] * 8 + (u & 7)] + (u >> 3)] = src[e];
  }
}

// x[row][j] = sum_k (ns[row]*h[row][k]) * W[k][j]    K = 128
// Block = 64 rows x DO cols (DO/64 col-halves processed sequentially).
// 256 threads = 16 rq x 16 cq, 4x4 outputs per thread per half.
// hs[64][132]: row-major, coalesced staging, 132 => 16B-aligned rows and
// conflict-free b128 reads (4 rq addrs land on 2 bank-groups = free 2-way).
// wl[128][64]: staged per half, reads 2-way broadcast (free).
template <int DO>
__global__ __launch_bounds__(256, 2) void gemm_tile(const float* __restrict__ h,
                                                    const float* __restrict__ W,
                                                    const float* __restrict__ ns,
                                                    float* __restrict__ x) {
  constexpr int CH = DO / 64;
  __shared__ __align__(16) float hs[64 * 132];  // 33.8 KB
  __shared__ __align__(16) float wl[128 * 64];  // 32 KB
  const int tid = threadIdx.x;
  const int row0 = blockIdx.x * 64;

  // stage hs with ns folded: coalesced (32 lanes x float4 = 512B per row)
#pragma unroll
  for (int it = 0; it < 8; ++it) {
    int flat = it * 256 + tid;
    int row = flat >> 5;
    int c = flat & 31;
    int grow = row0 + row;
    float4 hv = make_float4(0.f, 0.f, 0.f, 0.f);
    float sc = 0.f;
    if (grow < NN) {
      hv = *reinterpret_cast<const float4*>(&h[(size_t)grow * 128 + c * 4]);
      sc = ns[grow];
    }
    float* d = &hs[row * 132 + c * 4];
    d[0] = hv.x * sc; d[1] = hv.y * sc; d[2] = hv.z * sc; d[3] = hv.w * sc;
  }

  const int rq = tid >> 4;
  const int cq = tid & 15;

  for (int ch = 0; ch < CH; ++ch) {
    __syncthreads();  // ch=0: hs ready; ch>0: wl no longer being read
    // stage W col-half [128][64], fully coalesced
#pragma unroll
    for (int it = 0; it < 8; ++it) {
      int flat = it * 256 + tid;
      int k = flat >> 4;
      int c4 = flat & 15;
      *reinterpret_cast<float4*>(&wl[k * 64 + c4 * 4]) =
          *reinterpret_cast<const float4*>(&W[k * DO + ch * 64 + c4 * 4]);
    }
    __syncthreads();

    float acc[4][4] = {{0.f}};
#pragma unroll 4
    for (int k4 = 0; k4 < 32; ++k4) {
      float hv[4][4], wv[4][4];
#pragma unroll
      for (int i = 0; i < 4; ++i) {
        float4 t = *reinterpret_cast<const float4*>(&hs[(rq * 4 + i) * 132 + k4 * 4]);
        hv[i][0] = t.x; hv[i][1] = t.y; hv[i][2] = t.z; hv[i][3] = t.w;
      }
#pragma unroll
      for (int kk = 0; kk < 4; ++kk) {
        float4 t = *reinterpret_cast<const float4*>(&wl[(k4 * 4 + kk) * 64 + cq * 4]);
        wv[kk][0] = t.x; wv[kk][1] = t.y; wv[kk][2] = t.z; wv[kk][3] = t.w;
      }
#pragma unroll
      for (int i = 0; i < 4; ++i)
#pragma unroll
        for (int kk = 0; kk < 4; ++kk)
#pragma unroll
          for (int j = 0; j < 4; ++j)
            acc[i][j] = fmaf(hv[i][kk], wv[kk][j], acc[i][j]);
    }

#pragma unroll
    for (int i = 0; i < 4; ++i) {
      int row = row0 + rq * 4 + i;
      if (row < NN) {
        *reinterpret_cast<float4*>(&x[(size_t)row * DO + ch * 64 + cq * 4]) =
            make_float4(acc[i][0], acc[i][1], acc[i][2], acc[i][3]);
      }
    }
  }
}

// One wave per node. sub = lane/LPR edge slot, c4 = (lane%LPR)*4 column.
// LPR lanes cover a D-dim row with float4; EPW edge slots, 4 edges/slot in
// flight. Slot partials combined by shfl_xor; lanes < LPR write float4 out.
template <int D, bool RELU>
__global__ __launch_bounds__(256) void gather_kernel(const float* __restrict__ x,
                                                     const int* __restrict__ rowptr,
                                                     const int* __restrict__ col,
                                                     const float* __restrict__ nd,
                                                     const float* __restrict__ b,
                                                     float* __restrict__ out) {
  constexpr int LPR = D / 4;     // 32 (D=128) or 16 (D=64)
  constexpr int EPW = 64 / LPR;  // 2 or 4
  const int wid = (blockIdx.x * blockDim.x + threadIdx.x) >> 6;
  const int lane = threadIdx.x & 63;
  if (wid >= NN) return;
  const int sub = lane / LPR;
  const int c4 = (lane % LPR) * 4;
  const int beg = rowptr[wid];
  const int end = rowptr[wid + 1];

  float ax = 0.f, ay = 0.f, az = 0.f, aw = 0.f;
  int e = beg + sub;
  for (; e + 3 * EPW < end; e += 4 * EPW) {
    int c0 = col[e];
    int c1 = col[e + EPW];
    int c2 = col[e + 2 * EPW];
    int c3 = col[e + 3 * EPW];
    float4 v0 = *reinterpret_cast<const float4*>(&x[(size_t)c0 * D + c4]);
    float4 v1 = *reinterpret_cast<const float4*>(&x[(size_t)c1 * D + c4]);
    float4 v2 = *reinterpret_cast<const float4*>(&x[(size_t)c2 * D + c4]);
    float4 v3 = *reinterpret_cast<const float4*>(&x[(size_t)c3 * D + c4]);
    ax += (v0.x + v1.x) + (v2.x + v3.x);
    ay += (v0.y + v1.y) + (v2.y + v3.y);
    az += (v0.z + v1.z) + (v2.z + v3.z);
    aw += (v0.w + v1.w) + (v2.w + v3.w);
  }
  for (; e < end; e += EPW) {
    int c0 = col[e];
    float4 v0 = *reinterpret_cast<const float4*>(&x[(size_t)c0 * D + c4]);
    ax += v0.x; ay += v0.y; az += v0.z; aw += v0.w;
  }

#pragma unroll
  for (int off = LPR; off < 64; off <<= 1) {
    ax += __shfl_xor(ax, off, 64);
    ay += __shfl_xor(ay, off, 64);
    az += __shfl_xor(az, off, 64);
    aw += __shfl_xor(aw, off, 64);
  }

  if (lane < LPR) {
    const float s = nd[wid];
    float4 bb = *reinterpret_cast<const float4*>(&b[c4]);
    float4 r;
    r.x = fmaf(ax, s, bb.x);
    r.y = fmaf(ay, s, bb.y);
    r.z = fmaf(az, s, bb.z);
    r.w = fmaf(aw, s, bb.w);
    if (RELU) {
      r.x = fmaxf(r.x, 0.f);
      r.y = fmaxf(r.y, 0.f);
      r.z = fmaxf(r.z, 0.f);
      r.w = fmaxf(r.w, 0.f);
    }
    *reinterpret_cast<float4*>(&out[(size_t)wid * D + c4]) = r;
  }
}

}  // namespace

extern "C" void kernel_launch(void* const* d_in, const int* in_sizes, int n_in,
                              void* d_out, int out_size, void* d_ws, size_t ws_size,
                              hipStream_t stream) {
  const float* h0  = (const float*)d_in[0];
  const int*   src = (const int*)d_in[1];
  const int*   dst = (const int*)d_in[2];
  const float* W0 = (const float*)d_in[3];
  const float* b0 = (const float*)d_in[4];
  const float* W1 = (const float*)d_in[5];
  const float* b1 = (const float*)d_in[6];
  const float* W2 = (const float*)d_in[7];
  const float* b2 = (const float*)d_in[8];
  const float* W3 = (const float*)d_in[9];
  const float* b3 = (const float*)d_in[10];
  float* out = (float*)d_out;

  // workspace layout (256B aligned)
  char* w = (char*)d_ws;
  size_t off = 0;
  auto take = [&](size_t bytes) {
    char* p = w + off;
    off = (off + bytes + 255) & ~size_t(255);
    return p;
  };
  int*   dego8    = (int*)take((size_t)8 * NNP * 4);  // adjacent with degi8:
  int*   degi8    = (int*)take((size_t)8 * NNP * 4);  // one memset covers both
  int*   degi_tot = (int*)take(NN * 4);
  float* nsrc     = (float*)take(NN * 4);
  float* ndst     = (float*)take(NN * 4);
  int*   rowptr   = (int*)take((NN + 1) * 4);
  int*   offp     = (int*)take((size_t)NN * 8 * 4);
  int*   le       = (int*)take(NE * 4);
  int*   col      = (int*)take(NE * 4);
  int*   bsum     = (int*)take(NBLK * 4);
  int*   bpre     = (int*)take(NBLK * 4);
  float* xbuf     = (float*)take((size_t)NN * 128 * 4);
  float* hbuf     = (float*)take((size_t)NN * 128 * 4);
  (void)ws_size; (void)in_sizes; (void)n_in; (void)out_size;

  // zero both histogram replica arrays (contiguous)
  hipMemsetAsync(dego8, 0, (size_t)((char*)degi_tot - (char*)dego8), stream);

  const int EB = (NE + 255) / 256;
  const int NB = (NN + 255) / 256;
  deg8_kernel<<<EB, 256, 0, stream>>>(src, dst, dego8, degi8, le);
  reduce_norm_kernel<<<NB, 256, 0, stream>>>(dego8, degi8, degi_tot, nsrc, ndst, offp);
  scan_phase1<<<NBLK, SCAN_BLK, 0, stream>>>(degi_tot, bsum);
  scan_phase2<<<1, 256, 0, stream>>>(bsum, bpre, rowptr);
  scan_phase3<<<NBLK, SCAN_BLK, 0, stream>>>(degi_tot, bpre, rowptr);
  finalize_off_kernel<<<NB, 256, 0, stream>>>(rowptr, offp);
  scatter_kernel<<<EB, 256, 0, stream>>>(src, dst, le, offp, col);

  const int GEMM_BLOCKS = (NN + 63) / 64;  // 782
  const int GATHER_BLOCKS = (NN * 64 + 255) / 256;

  // layer 0: h0 -> x -> hbuf (relu)
  gemm_tile<128><<<GEMM_BLOCKS, 256, 0, stream>>>(h0, W0, nsrc, xbuf);
  gather_kernel<128, true><<<GATHER_BLOCKS, 256, 0, stream>>>(xbuf, rowptr, col, ndst, b0, hbuf);
  // layer 1
  gemm_tile<128><<<GEMM_BLOCKS, 256, 0, stream>>>(hbuf, W1, nsrc, xbuf);
  gather_kernel<128, true><<<GATHER_BLOCKS, 256, 0, stream>>>(xbuf, rowptr, col, ndst, b1, hbuf);
  // layer 2
  gemm_tile<128><<<GEMM_BLOCKS, 256, 0, stream>>>(hbuf, W2, nsrc, xbuf);
  gather_kernel<128, true><<<GATHER_BLOCKS, 256, 0, stream>>>(xbuf, rowptr, col, ndst, b2, hbuf);
  // layer 3: no relu, D=64, straight to d_out
  gemm_tile<64><<<GEMM_BLOCKS, 256, 0, stream>>>(hbuf, W3, nsrc, xbuf);
  gather_kernel<64, false><<<GATHER_BLOCKS, 256, 0, stream>>>(xbuf, rowptr, col, ndst, b3, out);
}

// Round 9
// 346.131 us; speedup vs baseline: 1.1365x; 1.0641x over previous
//
#include <hip/hip_runtime.h>

// GCN 4-layer forward on MI355X.
// Reference: h' = relu( norm_dst * segsum_{dst}( ((h*norm_src) @ W)[src] ) + b )
//
// Round 9:
//  - r8 lesson: device atomics execute at the coherence point (past per-XCD
//    L2) — sharding can't help; 1.2M atomics = ~50us of fabric wait at ~0%
//    VALU. So OVERLAP it: fused kernel = deg/le atomics (blocks 0..255,
//    grid-stride) + layer-0 GEMM tiles (blocks 256.., x0 = h0@W0 UNSCALED —
//    breaks the ns dependency). ns[col] folded into gather-0 instead.
//  - prep reverted to r7 single-histogram + le + atomic-free scatter.

namespace {

constexpr int NN = 50000;      // nodes
constexpr int NE = 600000;     // edges
constexpr int SCAN_BLK = 256;
constexpr int NBLK = (NN + SCAN_BLK - 1) / SCAN_BLK;  // 196
constexpr int DEG_BLOCKS = 256;
constexpr int GEMM_TILES = (NN + 63) / 64;            // 782

__global__ void norm_kernel(const int* __restrict__ dego, const int* __restrict__ degi,
                            float* __restrict__ ns, float* __restrict__ nd) {
  int i = blockIdx.x * blockDim.x + threadIdx.x;
  if (i < NN) {
    int a = dego[i]; if (a < 1) a = 1;
    int b = degi[i]; if (b < 1) b = 1;
    ns[i] = 1.0f / sqrtf((float)a);
    nd[i] = 1.0f / sqrtf((float)b);
  }
}

// --- 3-phase scan of degi[NN] -> rowptr[NN+1] (exclusive) ---

__global__ __launch_bounds__(SCAN_BLK) void scan_phase1(const int* __restrict__ deg,
                                                        int* __restrict__ bsum) {
  __shared__ int ws[SCAN_BLK / 64];
  int i = blockIdx.x * SCAN_BLK + threadIdx.x;
  int v = (i < NN) ? deg[i] : 0;
#pragma unroll
  for (int off = 32; off; off >>= 1) v += __shfl_down(v, off, 64);
  int lane = threadIdx.x & 63, w = threadIdx.x >> 6;
  if (lane == 0) ws[w] = v;
  __syncthreads();
  if (threadIdx.x == 0) {
    int s = 0;
#pragma unroll
    for (int k = 0; k < SCAN_BLK / 64; ++k) s += ws[k];
    bsum[blockIdx.x] = s;
  }
}

__global__ __launch_bounds__(256) void scan_phase2(const int* __restrict__ bsum,
                                                   int* __restrict__ bpre,
                                                   int* __restrict__ rowptr) {
  __shared__ int s[256];
  int t = threadIdx.x;
  int v = (t < NBLK) ? bsum[t] : 0;
  s[t] = v;
  __syncthreads();
  for (int off = 1; off < 256; off <<= 1) {
    int u = (t >= off) ? s[t - off] : 0;
    __syncthreads();
    s[t] += u;
    __syncthreads();
  }
  if (t < NBLK) bpre[t] = s[t] - v;  // exclusive
  if (t == 255) rowptr[NN] = s[255]; // total == NE
}

__global__ __launch_bounds__(SCAN_BLK) void scan_phase3(const int* __restrict__ deg,
                                                        const int* __restrict__ bpre,
                                                        int* __restrict__ rowptr) {
  __shared__ int s[SCAN_BLK];
  int t = threadIdx.x;
  int i = blockIdx.x * SCAN_BLK + t;
  int v = (i < NN) ? deg[i] : 0;
  s[t] = v;
  __syncthreads();
  for (int off = 1; off < SCAN_BLK; off <<= 1) {
    int u = (t >= off) ? s[t - off] : 0;
    __syncthreads();
    s[t] += u;
    __syncthreads();
  }
  if (i < NN) rowptr[i] = bpre[blockIdx.x] + s[t] - v;
}

// atomic-free CSR fill using le slots recorded during counting
__global__ void scatter_kernel(const int* __restrict__ src, const int* __restrict__ dst,
                               const int* __restrict__ le, const int* __restrict__ rowptr,
                               int* __restrict__ col) {
  int e = blockIdx.x * blockDim.x + threadIdx.x;
  if (e < NE) col[rowptr[dst[e]] + le[e]] = src[e];
}

// ---- GEMM tile body (shared by fused layer-0 kernel and plain kernels) ----
// x[row][j] = sum_k (opt ns[row] *) h[row][k] * W[k][j]    K = 128
// 64 rows x DO cols per tile; 256 threads = 16rq x 16cq, 4x4 per col-half.
// hs[64][132] row-major (coalesced staging, padded: conflict-free b128);
// wl[128][64] per half (2-way broadcast reads, free). 66.5KB LDS, 2 blk/CU.
template <int DO, bool USE_NS>
__device__ void gemm_body(const float* __restrict__ h, const float* __restrict__ W,
                          const float* __restrict__ ns, float* __restrict__ x,
                          int row0) {
  constexpr int CH = DO / 64;
  __shared__ __align__(16) float hs[64 * 132];  // 33.8 KB
  __shared__ __align__(16) float wl[128 * 64];  // 32 KB
  const int tid = threadIdx.x;

  // stage hs (optionally ns-folded): coalesced (32 lanes x float4 per row)
#pragma unroll
  for (int it = 0; it < 8; ++it) {
    int flat = it * 256 + tid;
    int row = flat >> 5;
    int c = flat & 31;
    int grow = row0 + row;
    float4 hv = make_float4(0.f, 0.f, 0.f, 0.f);
    float sc = 0.f;
    if (grow < NN) {
      hv = *reinterpret_cast<const float4*>(&h[(size_t)grow * 128 + c * 4]);
      sc = USE_NS ? ns[grow] : 1.0f;
    }
    float* d = &hs[row * 132 + c * 4];
    d[0] = hv.x * sc; d[1] = hv.y * sc; d[2] = hv.z * sc; d[3] = hv.w * sc;
  }

  const int rq = tid >> 4;
  const int cq = tid & 15;

  for (int ch = 0; ch < CH; ++ch) {
    __syncthreads();  // ch=0: hs ready; ch>0: wl no longer being read
#pragma unroll
    for (int it = 0; it < 8; ++it) {
      int flat = it * 256 + tid;
      int k = flat >> 4;
      int c4 = flat & 15;
      *reinterpret_cast<float4*>(&wl[k * 64 + c4 * 4]) =
          *reinterpret_cast<const float4*>(&W[k * DO + ch * 64 + c4 * 4]);
    }
    __syncthreads();

    float acc[4][4] = {{0.f}};
#pragma unroll 4
    for (int k4 = 0; k4 < 32; ++k4) {
      float hv[4][4], wv[4][4];
#pragma unroll
      for (int i = 0; i < 4; ++i) {
        float4 t = *reinterpret_cast<const float4*>(&hs[(rq * 4 + i) * 132 + k4 * 4]);
        hv[i][0] = t.x; hv[i][1] = t.y; hv[i][2] = t.z; hv[i][3] = t.w;
      }
#pragma unroll
      for (int kk = 0; kk < 4; ++kk) {
        float4 t = *reinterpret_cast<const float4*>(&wl[(k4 * 4 + kk) * 64 + cq * 4]);
        wv[kk][0] = t.x; wv[kk][1] = t.y; wv[kk][2] = t.z; wv[kk][3] = t.w;
      }
#pragma unroll
      for (int i = 0; i < 4; ++i)
#pragma unroll
        for (int kk = 0; kk < 4; ++kk)
#pragma unroll
          for (int j = 0; j < 4; ++j)
            acc[i][j] = fmaf(hv[i][kk], wv[kk][j], acc[i][j]);
    }

#pragma unroll
    for (int i = 0; i < 4; ++i) {
      int row = row0 + rq * 4 + i;
      if (row < NN) {
        *reinterpret_cast<float4*>(&x[(size_t)row * DO + ch * 64 + cq * 4]) =
            make_float4(acc[i][0], acc[i][1], acc[i][2], acc[i][3]);
      }
    }
  }
}

// Fused: blocks [0,DEG_BLOCKS) run degree counting + le (fire atomics from
// t=0; fabric-bound ~50us, ~0% VALU); blocks [DEG_BLOCKS, +GEMM_TILES) run
// layer-0 GEMM tiles (x0 = h0 @ W0, unscaled). GEMM work hides under the
// atomic drain window.
__global__ __launch_bounds__(256, 2) void gemm0_deg_kernel(
    const float* __restrict__ h, const float* __restrict__ W,
    float* __restrict__ x,
    const int* __restrict__ src, const int* __restrict__ dst,
    int* __restrict__ dego, int* __restrict__ degi, int* __restrict__ le) {
  if (blockIdx.x < DEG_BLOCKS) {
    const int stride = DEG_BLOCKS * 256;
    for (int e = blockIdx.x * 256 + threadIdx.x; e < NE; e += stride) {
      atomicAdd(&dego[src[e]], 1);
      int slot = atomicAdd(&degi[dst[e]], 1);
      le[e] = slot;
    }
    return;
  }
  gemm_body<128, false>(h, W, nullptr, x, (blockIdx.x - DEG_BLOCKS) * 64);
}

template <int DO>
__global__ __launch_bounds__(256, 2) void gemm_ns(const float* __restrict__ h,
                                                  const float* __restrict__ W,
                                                  const float* __restrict__ ns,
                                                  float* __restrict__ x) {
  gemm_body<DO, true>(h, W, ns, x, blockIdx.x * 64);
}

// One wave per node. sub = lane/LPR edge slot, c4 = (lane%LPR)*4 column.
// LPR lanes cover a D-dim row with float4; EPW edge slots, 4 edges/slot in
// flight. NSRC: multiply each edge row by ns[col] (layer 0 only — x0 is
// unscaled there). Slot partials combined by shfl_xor; lanes < LPR write
// float4 out with nd/bias/relu fused.
template <int D, bool RELU, bool NSRC>
__global__ __launch_bounds__(256) void gather_kernel(const float* __restrict__ x,
                                                     const int* __restrict__ rowptr,
                                                     const int* __restrict__ col,
                                                     const float* __restrict__ nd,
                                                     const float* __restrict__ b,
                                                     const float* __restrict__ nsv,
                                                     float* __restrict__ out) {
  constexpr int LPR = D / 4;     // 32 (D=128) or 16 (D=64)
  constexpr int EPW = 64 / LPR;  // 2 or 4
  const int wid = (blockIdx.x * blockDim.x + threadIdx.x) >> 6;
  const int lane = threadIdx.x & 63;
  if (wid >= NN) return;
  const int sub = lane / LPR;
  const int c4 = (lane % LPR) * 4;
  const int beg = rowptr[wid];
  const int end = rowptr[wid + 1];

  float ax = 0.f, ay = 0.f, az = 0.f, aw = 0.f;
  int e = beg + sub;
  for (; e + 3 * EPW < end; e += 4 * EPW) {
    int c0 = col[e];
    int c1 = col[e + EPW];
    int c2 = col[e + 2 * EPW];
    int c3 = col[e + 3 * EPW];
    float s0 = NSRC ? nsv[c0] : 1.0f;
    float s1 = NSRC ? nsv[c1] : 1.0f;
    float s2 = NSRC ? nsv[c2] : 1.0f;
    float s3 = NSRC ? nsv[c3] : 1.0f;
    float4 v0 = *reinterpret_cast<const float4*>(&x[(size_t)c0 * D + c4]);
    float4 v1 = *reinterpret_cast<const float4*>(&x[(size_t)c1 * D + c4]);
    float4 v2 = *reinterpret_cast<const float4*>(&x[(size_t)c2 * D + c4]);
    float4 v3 = *reinterpret_cast<const float4*>(&x[(size_t)c3 * D + c4]);
    if (NSRC) {
      ax = fmaf(s0, v0.x, fmaf(s1, v1.x, fmaf(s2, v2.x, fmaf(s3, v3.x, ax))));
      ay = fmaf(s0, v0.y, fmaf(s1, v1.y, fmaf(s2, v2.y, fmaf(s3, v3.y, ay))));
      az = fmaf(s0, v0.z, fmaf(s1, v1.z, fmaf(s2, v2.z, fmaf(s3, v3.z, az))));
      aw = fmaf(s0, v0.w, fmaf(s1, v1.w, fmaf(s2, v2.w, fmaf(s3, v3.w, aw))));
    } else {
      ax += (v0.x + v1.x) + (v2.x + v3.x);
      ay += (v0.y + v1.y) + (v2.y + v3.y);
      az += (v0.z + v1.z) + (v2.z + v3.z);
      aw += (v0.w + v1.w) + (v2.w + v3.w);
    }
  }
  for (; e < end; e += EPW) {
    int c0 = col[e];
    float s0 = NSRC ? nsv[c0] : 1.0f;
    float4 v0 = *reinterpret_cast<const float4*>(&x[(size_t)c0 * D + c4]);
    ax = fmaf(s0, v0.x, ax);
    ay = fmaf(s0, v0.y, ay);
    az = fmaf(s0, v0.z, az);
    aw = fmaf(s0, v0.w, aw);
  }

#pragma unroll
  for (int off = LPR; off < 64; off <<= 1) {
    ax += __shfl_xor(ax, off, 64);
    ay += __shfl_xor(ay, off, 64);
    az += __shfl_xor(az, off, 64);
    aw += __shfl_xor(aw, off, 64);
  }

  if (lane < LPR) {
    const float s = nd[wid];
    float4 bb = *reinterpret_cast<const float4*>(&b[c4]);
    float4 r;
    r.x = fmaf(ax, s, bb.x);
    r.y = fmaf(ay, s, bb.y);
    r.z = fmaf(az, s, bb.z);
    r.w = fmaf(aw, s, bb.w);
    if (RELU) {
      r.x = fmaxf(r.x, 0.f);
      r.y = fmaxf(r.y, 0.f);
      r.z = fmaxf(r.z, 0.f);
      r.w = fmaxf(r.w, 0.f);
    }
    *reinterpret_cast<float4*>(&out[(size_t)wid * D + c4]) = r;
  }
}

}  // namespace

extern "C" void kernel_launch(void* const* d_in, const int* in_sizes, int n_in,
                              void* d_out, int out_size, void* d_ws, size_t ws_size,
                              hipStream_t stream) {
  const float* h0  = (const float*)d_in[0];
  const int*   src = (const int*)d_in[1];
  const int*   dst = (const int*)d_in[2];
  const float* W0 = (const float*)d_in[3];
  const float* b0 = (const float*)d_in[4];
  const float* W1 = (const float*)d_in[5];
  const float* b1 = (const float*)d_in[6];
  const float* W2 = (const float*)d_in[7];
  const float* b2 = (const float*)d_in[8];
  const float* W3 = (const float*)d_in[9];
  const float* b3 = (const float*)d_in[10];
  float* out = (float*)d_out;

  // workspace layout (256B aligned)
  char* w = (char*)d_ws;
  size_t off = 0;
  auto take = [&](size_t bytes) {
    char* p = w + off;
    off = (off + bytes + 255) & ~size_t(255);
    return p;
  };
  int*   deg_out = (int*)take(NN * 4);   // adjacent: one memset covers both
  int*   deg_in  = (int*)take(NN * 4);
  float* nsrc    = (float*)take(NN * 4);
  float* ndst    = (float*)take(NN * 4);
  int*   rowptr  = (int*)take((NN + 1) * 4);
  int*   le      = (int*)take(NE * 4);
  int*   col     = (int*)take(NE * 4);
  int*   bsum    = (int*)take(NBLK * 4);
  int*   bpre    = (int*)take(NBLK * 4);
  float* xbuf    = (float*)take((size_t)NN * 128 * 4);
  float* hbuf    = (float*)take((size_t)NN * 128 * 4);
  (void)ws_size; (void)in_sizes; (void)n_in; (void)out_size;

  // zero both degree arrays (contiguous)
  hipMemsetAsync(deg_out, 0, (size_t)((char*)nsrc - (char*)deg_out), stream);

  const int EB = (NE + 255) / 256;
  const int NB = (NN + 255) / 256;

  // fused: degree atomics (blocks 0..255) + layer-0 GEMM x0 = h0@W0 (rest)
  gemm0_deg_kernel<<<DEG_BLOCKS + GEMM_TILES, 256, 0, stream>>>(
      h0, W0, xbuf, src, dst, deg_out, deg_in, le);
  norm_kernel<<<NB, 256, 0, stream>>>(deg_out, deg_in, nsrc, ndst);
  scan_phase1<<<NBLK, SCAN_BLK, 0, stream>>>(deg_in, bsum);
  scan_phase2<<<1, 256, 0, stream>>>(bsum, bpre, rowptr);
  scan_phase3<<<NBLK, SCAN_BLK, 0, stream>>>(deg_in, bpre, rowptr);
  scatter_kernel<<<EB, 256, 0, stream>>>(src, dst, le, rowptr, col);

  const int GATHER_BLOCKS = (NN * 64 + 255) / 256;

  // layer 0: x0 unscaled -> gather applies ns[col] inside the sum
  gather_kernel<128, true, true><<<GATHER_BLOCKS, 256, 0, stream>>>(
      xbuf, rowptr, col, ndst, b0, nsrc, hbuf);
  // layer 1
  gemm_ns<128><<<GEMM_TILES, 256, 0, stream>>>(hbuf, W1, nsrc, xbuf);
  gather_kernel<128, true, false><<<GATHER_BLOCKS, 256, 0, stream>>>(
      xbuf, rowptr, col, ndst, b1, nullptr, hbuf);
  // layer 2
  gemm_ns<128><<<GEMM_TILES, 256, 0, stream>>>(hbuf, W2, nsrc, xbuf);
  gather_kernel<128, true, false><<<GATHER_BLOCKS, 256, 0, stream>>>(
      xbuf, rowptr, col, ndst, b2, nullptr, hbuf);
  // layer 3: no relu, D=64, straight to d_out
  gemm_ns<64><<<GEMM_TILES, 256, 0, stream>>>(hbuf, W3, nsrc, xbuf);
  gather_kernel<64, false, false><<<GATHER_BLOCKS, 256, 0, stream>>>(
      xbuf, rowptr, col, ndst, b3, nullptr, out);
}